// Round 1
// baseline (75.511 us; speedup 1.0000x reference)
//
#include <hip/hip_runtime.h>
#include <cmath>

typedef float f32x4 __attribute__((ext_vector_type(4)));

#define TT 8192
#define NV 65

__device__ __forceinline__ float dot4acc(f32x4 a, f32x4 b, float acc) {
  acc = fmaf(a[0], b[0], acc);
  acc = fmaf(a[1], b[1], acc);
  acc = fmaf(a[2], b[2], acc);
  acc = fmaf(a[3], b[3], acc);
  return acc;
}

// Kernel A: class_prob = softmax(embed_w[x]) -> CP_T[24][8192], CP_T[b*6+e][t]
__global__ __launch_bounds__(256) void cp_kernel(const int* __restrict__ x,
                                                 const float* __restrict__ ew,
                                                 float* __restrict__ cpt) {
  int n = blockIdx.x * 256 + threadIdx.x;  // n = b*8192 + t
  int b = n >> 13, t = n & 8191;
  int xv = x[n];
  float v[6];
#pragma unroll
  for (int e = 0; e < 6; ++e) v[e] = ew[xv * 6 + e];
  float m = v[0];
#pragma unroll
  for (int e = 1; e < 6; ++e) m = fmaxf(m, v[e]);
  float s = 0.f;
#pragma unroll
  for (int e = 0; e < 6; ++e) { v[e] = expf(v[e] - m); s += v[e]; }
  float inv = 1.f / s;
#pragma unroll
  for (int e = 0; e < 6; ++e) cpt[(b * 6 + e) * TT + t] = v[e] * inv;
}

// Kernel B: wsum[t][24] = sum_{k<=t} W[t][k] * CP_T[:][k], then epilogue.
// Block j: waves 0,1 -> rows [8j, 8j+8); waves 2,3 -> rows [8184-8j, 8192-8j).
// Each wave owns 4 consecutive rows; lanes split k (4 consecutive k per lane).
__global__ __launch_bounds__(256) void sticky_main(
    const float* __restrict__ W, const float* __restrict__ cpt,
    const float* __restrict__ rtp, const float* __restrict__ tp,
    const float* __restrict__ CT, const float* __restrict__ RT,
    const float* __restrict__ OM, float* __restrict__ out) {
  __shared__ __align__(16) float cp_lds[24][256];
  __shared__ __align__(16) float wsum_lds[4][4][24];
  const int j = blockIdx.x;
  const int tid = threadIdx.x;
  const int w = tid >> 6, lane = tid & 63;
  const int rbase = (w < 2) ? (8 * j + 4 * w) : (8184 - 8 * j + 4 * (w - 2));
  const int wmax = rbase + 3;          // last row this wave owns
  const int k_need = 8192 - 8 * j;     // block-uniform k extent (max row + 1)
  const int kl = lane * 4;

  float acc[4][24];
#pragma unroll
  for (int r = 0; r < 4; ++r)
#pragma unroll
    for (int e = 0; e < 24; ++e) acc[r][e] = 0.f;

  for (int kc = 0; kc < k_need; kc += 256) {
    __syncthreads();
    // stage CP_T[0..24)[kc..kc+256) into LDS (24 KB), 6 float4 per thread
#pragma unroll
    for (int i = 0; i < 6; ++i) {
      int f = tid + 256 * i;            // 0..1535 float4 slots
      int e = f >> 6, c4 = (f & 63) * 4;
      *reinterpret_cast<f32x4*>(&cp_lds[e][c4]) =
          *reinterpret_cast<const f32x4*>(&cpt[e * TT + kc + c4]);
    }
    __syncthreads();
    if (kc <= wmax) {  // wave-uniform; beyond its diagonal the wave is done
      // upper-triangle of position_mask is exactly 0 (setup applies tril),
      // so in-row over-read past the diagonal contributes nothing.
      const float* wp = &W[(size_t)rbase * TT + kc + kl];
      f32x4 w0 = __builtin_nontemporal_load(reinterpret_cast<const f32x4*>(wp));
      f32x4 w1 = __builtin_nontemporal_load(reinterpret_cast<const f32x4*>(wp + TT));
      f32x4 w2 = __builtin_nontemporal_load(reinterpret_cast<const f32x4*>(wp + 2 * TT));
      f32x4 w3 = __builtin_nontemporal_load(reinterpret_cast<const f32x4*>(wp + 3 * TT));
#pragma unroll
      for (int e = 0; e < 24; ++e) {
        f32x4 c = *reinterpret_cast<const f32x4*>(&cp_lds[e][kl]);
        acc[0][e] = dot4acc(w0, c, acc[0][e]);
        acc[1][e] = dot4acc(w1, c, acc[1][e]);
        acc[2][e] = dot4acc(w2, c, acc[2][e]);
        acc[3][e] = dot4acc(w3, c, acc[3][e]);
      }
    }
  }

  // butterfly reduce 96 partials across the 64 lanes
#pragma unroll
  for (int r = 0; r < 4; ++r)
#pragma unroll
    for (int e = 0; e < 24; ++e) {
      float v0 = acc[r][e];
      v0 += __shfl_xor(v0, 1);
      v0 += __shfl_xor(v0, 2);
      v0 += __shfl_xor(v0, 4);
      v0 += __shfl_xor(v0, 8);
      v0 += __shfl_xor(v0, 16);
      v0 += __shfl_xor(v0, 32);
      acc[r][e] = v0;
    }
  // park reduced sums in LDS so the epilogue's runtime (r,b) indexing
  // doesn't force the register array to scratch
  if (lane == 0) {
#pragma unroll
    for (int r = 0; r < 4; ++r)
#pragma unroll
      for (int g = 0; g < 6; ++g) {
        f32x4 t4;
        t4[0] = acc[r][4 * g + 0];
        t4[1] = acc[r][4 * g + 1];
        t4[2] = acc[r][4 * g + 2];
        t4[3] = acc[r][4 * g + 3];
        *reinterpret_cast<f32x4*>(&wsum_lds[w][r][4 * g]) = t4;
      }
  }
  __syncthreads();

  // epilogue: lane -> (r,b) pair + v-chunk; 4 rows x 4 batches x 65 outputs
  const int rb = lane & 15;
  const int r = rb >> 2, b = rb & 3, vi = lane >> 4;
  const int t = rbase + r;
  float cp6[6], ws6[6];
#pragma unroll
  for (int e = 0; e < 6; ++e) {
    cp6[e] = cpt[(b * 6 + e) * TT + t];
    ws6[e] = wsum_lds[w][r][b * 6 + e];
  }
  float score = 0.f;
#pragma unroll
  for (int e = 0; e < 6; ++e) score = fmaf(cp6[e], ws6[e], score);
  float rt = rtp[0];
  float temp = tp[0];
  float z = (score - rt * rt) / (temp * temp);
  float reset = 1.f / (1.f + expf(-z));  // saturates correctly for |z| large
  float nc[6];
#pragma unroll
  for (int c = 0; c < 6; ++c) {
    float tc = 0.f, rc = 0.f;
#pragma unroll
    for (int e = 0; e < 6; ++e) {
      tc = fmaf(cp6[e], CT[e * 6 + c], tc);
      rc = fmaf(cp6[e], RT[e * 6 + c], rc);
    }
    nc[c] = reset * rc + (1.f - reset) * tc;
  }
  size_t obase = ((size_t)b * TT + t) * NV;
  for (int v = vi; v < NV; v += 4) {
    float o = 0.f;
#pragma unroll
    for (int c = 0; c < 6; ++c) o = fmaf(nc[c], OM[c * NV + v], o);
    out[obase + v] = o;
  }
}

extern "C" void kernel_launch(void* const* d_in, const int* in_sizes, int n_in,
                              void* d_out, int out_size, void* d_ws, size_t ws_size,
                              hipStream_t stream) {
  const int* x = (const int*)d_in[0];
  const float* ew = (const float*)d_in[1];
  const float* W = (const float*)d_in[2];
  const float* rtp = (const float*)d_in[3];
  const float* tp = (const float*)d_in[4];
  const float* CT = (const float*)d_in[5];
  const float* RT = (const float*)d_in[6];
  const float* OM = (const float*)d_in[7];
  float* out = (float*)d_out;
  float* cpt = (float*)d_ws;  // 24*8192*4 B = 786 KB

  hipLaunchKernelGGL(cp_kernel, dim3(128), dim3(256), 0, stream, x, ew, cpt);
  hipLaunchKernelGGL(sticky_main, dim3(512), dim3(256), 0, stream,
                     W, cpt, rtp, tp, CT, RT, OM, out);
}